// Round 1
// baseline (1034.509 us; speedup 1.0000x reference)
//
#include <hip/hip_runtime.h>

#define NODES 50000
#define EDGES 600000
#define C     128
#define NGRAPH 64
#define EPSBN 1e-5f

// ---------------- workspace layout (bytes) ----------------
// zeroed region (one hipMemsetAsync):
#define OFF_DEGCNT 0u          // int[50048]   -> 200192
#define OFF_CURSOR 200192u     // int[50048]   -> 400384
#define OFF_STATS  400384u     // float[768]   -> 403456   (layer l: sums l*256, sumsq l*256+128)
#define OFF_PSUM   403456u     // float[8192]  -> 436224
#define OFF_PCNT   436224u     // int[64]      -> 436480
#define ZERO_BYTES 436480u
// non-zeroed:
#define OFF_ROWPTR 436480u     // int[50056]   -> 636704
#define OFF_DINV   636704u     // float[50048] -> 836896
#define OFF_SS     836896u     // float[768]   -> 839968   (layer l: scale l*256, shift l*256+128)
#define OFF_COL    839968u     // int[600064]  -> 3240224
#define OFF_COEF   3240224u    // float[600064]-> 5640480
#define OFF_BUFH   5640480u    // float[6400000] -> 31240480
#define OFF_BUFA   31240480u   // float[6400000] -> 56840480

// ---------------- CSR build ----------------
__global__ void deg_kernel(const int* __restrict__ dst, int* __restrict__ degcnt) {
    int e = blockIdx.x * 256 + threadIdx.x;
    if (e < EDGES) atomicAdd(&degcnt[dst[e]], 1);
}

__global__ __launch_bounds__(1024) void scan_kernel(const int* __restrict__ degcnt,
                                                    int* __restrict__ rowptr,
                                                    float* __restrict__ dinv) {
    const int CHK = 49;  // 1024*49 = 50176 >= 50000
    int t = threadIdx.x;
    int base = t * CHK;
    int local = 0;
    for (int j = 0; j < CHK; j++) { int i = base + j; if (i < NODES) local += degcnt[i]; }
    __shared__ int sc[1024];
    sc[t] = local; __syncthreads();
    for (int off = 1; off < 1024; off <<= 1) {
        int v = 0; if (t >= off) v = sc[t - off];
        __syncthreads(); sc[t] += v; __syncthreads();
    }
    int run = sc[t] - local;  // exclusive prefix
    for (int j = 0; j < CHK; j++) {
        int i = base + j;
        if (i < NODES) {
            rowptr[i] = run;
            int c = degcnt[i]; run += c;
            dinv[i] = (c > 0) ? rsqrtf((float)c) : 0.f;
        }
    }
    if (t == 1023) rowptr[NODES] = sc[1023];
}

__global__ void fill_kernel(const int* __restrict__ src, const int* __restrict__ dst,
                            const int* __restrict__ rowptr, int* __restrict__ cursor,
                            const float* __restrict__ dinv,
                            int* __restrict__ col, float* __restrict__ coef) {
    int e = blockIdx.x * 256 + threadIdx.x;
    if (e < EDGES) {
        int s = src[e], d = dst[e];
        int pos = rowptr[d] + atomicAdd(&cursor[d], 1);
        col[pos] = s;
        coef[pos] = dinv[s] * dinv[d];
    }
}

// ---------------- GEMM: [NODES,128] @ [128,BNcols] with fused BN+ReLU on input ----------------
// block: 256 threads, computes 64 rows x 64 cols. LDS = 33792 + 32768 = 66560 B -> 2 blocks/CU.
__global__ __launch_bounds__(256) void gemm_kernel(
    const float* __restrict__ A, const float* __restrict__ W, float* __restrict__ Cm,
    const float* __restrict__ scale, const float* __restrict__ shift) {
    __shared__ float As[64 * 132];   // pad 132: A-read 2-way conflict only (free)
    __shared__ float Ws[128 * 64];
    int t = threadIdx.x;
    int r0 = blockIdx.x * 64;
    int c0 = blockIdx.y * 64;
    // stage A tile 64x128 (2048 float4, 8/thread), fused BN+ReLU
    #pragma unroll
    for (int j = 0; j < 8; j++) {
        int idx = t + 256 * j;
        int row = idx >> 5;
        int colv = (idx & 31) << 2;
        float4 v;
        int gr = r0 + row;
        if (gr < NODES) v = *(const float4*)&A[gr * C + colv];
        else            v = make_float4(0.f, 0.f, 0.f, 0.f);
        if (scale) {
            float4 sc = *(const float4*)&scale[colv];
            float4 sh = *(const float4*)&shift[colv];
            v.x = fmaxf(0.f, fmaf(v.x, sc.x, sh.x));
            v.y = fmaxf(0.f, fmaf(v.y, sc.y, sh.y));
            v.z = fmaxf(0.f, fmaf(v.z, sc.z, sh.z));
            v.w = fmaxf(0.f, fmaf(v.w, sc.w, sh.w));
        }
        *(float4*)&As[row * 132 + colv] = v;
    }
    // stage W tile 128x64 (2048 float4, 8/thread)
    #pragma unroll
    for (int j = 0; j < 8; j++) {
        int idx = t + 256 * j;
        int row = idx >> 4;
        int colv = (idx & 15) << 2;
        *(float4*)&Ws[row * 64 + colv] = *(const float4*)&W[row * C + c0 + colv];
    }
    __syncthreads();
    int tx = t & 15, ty = t >> 4;
    float acc[4][4] = {};
    for (int k0 = 0; k0 < 128; k0 += 4) {
        float4 a[4];
        #pragma unroll
        for (int i = 0; i < 4; i++) a[i] = *(const float4*)&As[(ty * 4 + i) * 132 + k0];
        #pragma unroll
        for (int kk = 0; kk < 4; kk++) {
            float4 w = *(const float4*)&Ws[(k0 + kk) * 64 + tx * 4];
            #pragma unroll
            for (int i = 0; i < 4; i++) {
                float av = ((const float*)&a[i])[kk];
                acc[i][0] = fmaf(av, w.x, acc[i][0]);
                acc[i][1] = fmaf(av, w.y, acc[i][1]);
                acc[i][2] = fmaf(av, w.z, acc[i][2]);
                acc[i][3] = fmaf(av, w.w, acc[i][3]);
            }
        }
    }
    #pragma unroll
    for (int i = 0; i < 4; i++) {
        int gr = r0 + ty * 4 + i;
        if (gr < NODES) {
            float4 v = make_float4(acc[i][0], acc[i][1], acc[i][2], acc[i][3]);
            *(float4*)&Cm[gr * C + c0 + tx * 4] = v;
        }
    }
}

// ---------------- aggregation: one wave per node, gather-only via CSR ----------------
__global__ __launch_bounds__(256) void agg_kernel(
    const float* __restrict__ H, const int* __restrict__ rowptr,
    const int* __restrict__ col, const float* __restrict__ coef,
    float* __restrict__ Aout) {
    int wid = (blockIdx.x * 256 + threadIdx.x) >> 6;
    int lane = threadIdx.x & 63;
    if (wid >= NODES) return;
    int beg = rowptr[wid], end = rowptr[wid + 1];
    float2 acc = make_float2(0.f, 0.f);
    for (int i = beg; i < end; i++) {
        int s = col[i];
        float w = coef[i];
        float2 h = *(const float2*)&H[s * C + lane * 2];
        acc.x = fmaf(w, h.x, acc.x);
        acc.y = fmaf(w, h.y, acc.y);
    }
    *(float2*)&Aout[wid * C + lane * 2] = acc;
}

// ---------------- BN stats: per-channel sum & sumsq ----------------
__global__ __launch_bounds__(256) void stats_kernel(const float* __restrict__ X,
                                                    float* __restrict__ stats) {
    int t = threadIdx.x;
    int c = t & 127, half = t >> 7;
    float s = 0.f, q = 0.f;
    for (int row = blockIdx.x * 2 + half; row < NODES; row += gridDim.x * 2) {
        float v = X[row * C + c];
        s += v; q = fmaf(v, v, q);
    }
    __shared__ float red[512];
    red[t] = s; red[256 + t] = q;
    __syncthreads();
    if (half == 0) {
        s += red[t + 128]; q += red[256 + t + 128];
        atomicAdd(&stats[c], s);
        atomicAdd(&stats[128 + c], q);
    }
}

__global__ void finalize_kernel(const float* __restrict__ stats, const float* __restrict__ g,
                                const float* __restrict__ be, float* __restrict__ ss) {
    int c = threadIdx.x;  // 128
    float mean = stats[c] * (1.0f / NODES);
    float var = stats[128 + c] * (1.0f / NODES) - mean * mean;
    float sc = g[c] * rsqrtf(var + EPSBN);
    ss[c] = sc;
    ss[128 + c] = be[c] - mean * sc;
}

// ---------------- pooling ----------------
__global__ void count_kernel(const int* __restrict__ batch, int* __restrict__ pcnt) {
    int n = blockIdx.x * 256 + threadIdx.x;
    if (n < NODES) atomicAdd(&pcnt[batch[n]], 1);
}

__global__ __launch_bounds__(128) void pool_kernel(const float* __restrict__ X,
                                                   const int* __restrict__ batch,
                                                   const float* __restrict__ ss,
                                                   float* __restrict__ psum) {
    int c = threadIdx.x;
    int r0 = blockIdx.x * 128;
    if (r0 >= NODES) return;
    int rend = min(r0 + 128, NODES);
    float sc = ss[c], sh = ss[128 + c];
    float acc = 0.f;
    int cur = batch[r0];
    for (int r = r0; r < rend; r++) {
        int g = batch[r];
        if (g != cur) { atomicAdd(&psum[cur * C + c], acc); acc = 0.f; cur = g; }
        float v = X[r * C + c];
        v = fmaxf(0.f, fmaf(v, sc, sh));
        acc += v;
    }
    atomicAdd(&psum[cur * C + c], acc);
}

__global__ void head_kernel(const float* __restrict__ psum, const int* __restrict__ pcnt,
                            const float* __restrict__ Wh, const float* __restrict__ bh,
                            float* __restrict__ out) {
    int t = threadIdx.x;  // 512
    int g = t >> 3, o = t & 7;
    float inv = 1.0f / fmaxf((float)pcnt[g], 1.0f);
    float acc = 0.f;
    for (int c = 0; c < C; c++) acc = fmaf(psum[g * C + c], Wh[c * 8 + o], acc);
    out[t] = fmaf(acc, inv, bh[o]);
}

extern "C" void kernel_launch(void* const* d_in, const int* in_sizes, int n_in,
                              void* d_out, int out_size, void* d_ws, size_t ws_size,
                              hipStream_t stream) {
    (void)in_sizes; (void)n_in; (void)out_size; (void)ws_size;
    const float* x    = (const float*)d_in[0];
    const int*   ei   = (const int*)d_in[1];      // [2, EDGES]: src then dst
    const int*   batch= (const int*)d_in[2];
    const float* W0   = (const float*)d_in[3];
    const float* g0   = (const float*)d_in[5];
    const float* be0  = (const float*)d_in[6];
    const float* W1   = (const float*)d_in[7];
    const float* g1   = (const float*)d_in[9];
    const float* be1  = (const float*)d_in[10];
    const float* W2   = (const float*)d_in[11];
    const float* g2   = (const float*)d_in[13];
    const float* be2  = (const float*)d_in[14];
    const float* Wh   = (const float*)d_in[15];
    const float* bh   = (const float*)d_in[16];
    float* out = (float*)d_out;

    char* ws = (char*)d_ws;
    int*   degcnt = (int*)(ws + OFF_DEGCNT);
    int*   cursor = (int*)(ws + OFF_CURSOR);
    float* stats  = (float*)(ws + OFF_STATS);
    float* psum   = (float*)(ws + OFF_PSUM);
    int*   pcnt   = (int*)(ws + OFF_PCNT);
    int*   rowptr = (int*)(ws + OFF_ROWPTR);
    float* dinv   = (float*)(ws + OFF_DINV);
    float* ss     = (float*)(ws + OFF_SS);
    int*   col    = (int*)(ws + OFF_COL);
    float* coef   = (float*)(ws + OFF_COEF);
    float* bufH   = (float*)(ws + OFF_BUFH);
    float* bufA   = (float*)(ws + OFF_BUFA);

    hipMemsetAsync(ws, 0, ZERO_BYTES, stream);

    const int EB = (EDGES + 255) / 256;
    deg_kernel<<<EB, 256, 0, stream>>>(ei + EDGES, degcnt);
    scan_kernel<<<1, 1024, 0, stream>>>(degcnt, rowptr, dinv);
    fill_kernel<<<EB, 256, 0, stream>>>(ei, ei + EDGES, rowptr, cursor, dinv, col, coef);

    dim3 gg((NODES + 63) / 64, 2);
    const int AGB = (NODES * 64 + 255) / 256;  // 12500

    // layer 0
    gemm_kernel<<<gg, 256, 0, stream>>>(x, W0, bufH, nullptr, nullptr);
    agg_kernel<<<AGB, 256, 0, stream>>>(bufH, rowptr, col, coef, bufA);
    stats_kernel<<<128, 256, 0, stream>>>(bufA, stats + 0);
    finalize_kernel<<<1, 128, 0, stream>>>(stats + 0, g0, be0, ss + 0);
    // layer 1 (BN0+ReLU fused into A-load)
    gemm_kernel<<<gg, 256, 0, stream>>>(bufA, W1, bufH, ss + 0, ss + 128);
    agg_kernel<<<AGB, 256, 0, stream>>>(bufH, rowptr, col, coef, bufA);
    stats_kernel<<<128, 256, 0, stream>>>(bufA, stats + 256);
    finalize_kernel<<<1, 128, 0, stream>>>(stats + 256, g1, be1, ss + 256);
    // layer 2
    gemm_kernel<<<gg, 256, 0, stream>>>(bufA, W2, bufH, ss + 256, ss + 384);
    agg_kernel<<<AGB, 256, 0, stream>>>(bufH, rowptr, col, coef, bufA);
    stats_kernel<<<128, 256, 0, stream>>>(bufA, stats + 512);
    finalize_kernel<<<1, 128, 0, stream>>>(stats + 512, g2, be2, ss + 512);
    // pool + head (BN2+ReLU fused into pool)
    count_kernel<<<(NODES + 255) / 256, 256, 0, stream>>>(batch, pcnt);
    pool_kernel<<<(NODES + 127) / 128, 128, 0, stream>>>(bufA, batch, ss + 512, psum);
    head_kernel<<<1, 512, 0, stream>>>(psum, pcnt, Wh, bh, out);
}

// Round 2
// 714.410 us; speedup vs baseline: 1.4481x; 1.4481x over previous
//
#include <hip/hip_runtime.h>

#define NODES 50000
#define EDGES 600000
#define C     128
#define NGRAPH 64
#define EPSBN 1e-5f

// ---------------- workspace layout (bytes) ----------------
// zeroed region (one hipMemsetAsync):
#define OFF_DEGCNT 0u          // int[50048]   -> 200192
#define OFF_CURSOR 200192u     // int[50048]   -> 400384
#define OFF_STATS  400384u     // float[768]   -> 403456   (layer l: sums l*256, sumsq l*256+128)
#define OFF_PSUM   403456u     // float[8192]  -> 436224
#define OFF_PCNT   436224u     // int[64]      -> 436480
#define ZERO_BYTES 436480u
// non-zeroed:
#define OFF_ROWPTR 436480u     // int[50056]   -> 636704
#define OFF_DINV   636704u     // float[50048] -> 836896
#define OFF_SS     836896u     // float[768]   -> 839968   (layer l: scale l*256, shift l*256+128)
#define OFF_COL    839968u     // int[600064]  -> 3240224
#define OFF_COEF   3240224u    // float[600064]-> 5640480
#define OFF_BUFH   5640480u    // float[6400000] -> 31240480
#define OFF_BUFA   31240480u   // float[6400000] -> 56840480

// ---------------- CSR build ----------------
__global__ void deg_kernel(const int* __restrict__ dst, int* __restrict__ degcnt) {
    int e = blockIdx.x * 256 + threadIdx.x;
    if (e < EDGES) atomicAdd(&degcnt[dst[e]], 1);
}

__global__ __launch_bounds__(1024) void scan_kernel(const int* __restrict__ degcnt,
                                                    int* __restrict__ rowptr,
                                                    float* __restrict__ dinv) {
    const int CHK = 49;  // 1024*49 = 50176 >= 50000
    int t = threadIdx.x;
    int base = t * CHK;
    int local = 0;
    for (int j = 0; j < CHK; j++) { int i = base + j; if (i < NODES) local += degcnt[i]; }
    __shared__ int sc[1024];
    sc[t] = local; __syncthreads();
    for (int off = 1; off < 1024; off <<= 1) {
        int v = 0; if (t >= off) v = sc[t - off];
        __syncthreads(); sc[t] += v; __syncthreads();
    }
    int run = sc[t] - local;  // exclusive prefix
    for (int j = 0; j < CHK; j++) {
        int i = base + j;
        if (i < NODES) {
            rowptr[i] = run;
            int c = degcnt[i]; run += c;
            dinv[i] = (c > 0) ? rsqrtf((float)c) : 0.f;
        }
    }
    if (t == 1023) rowptr[NODES] = sc[1023];
}

__global__ void fill_kernel(const int* __restrict__ src, const int* __restrict__ dst,
                            const int* __restrict__ rowptr, int* __restrict__ cursor,
                            const float* __restrict__ dinv,
                            int* __restrict__ col, float* __restrict__ coef) {
    int e = blockIdx.x * 256 + threadIdx.x;
    if (e < EDGES) {
        int s = src[e], d = dst[e];
        int pos = rowptr[d] + atomicAdd(&cursor[d], 1);
        col[pos] = s;
        coef[pos] = dinv[s] * dinv[d];
    }
}

// ---------------- GEMM: [NODES,128] @ [128,BNcols] with fused BN+ReLU on input ----------------
// block: 256 threads, computes 64 rows x 64 cols. LDS = 33792 + 32768 = 66560 B -> 2 blocks/CU.
__global__ __launch_bounds__(256) void gemm_kernel(
    const float* __restrict__ A, const float* __restrict__ W, float* __restrict__ Cm,
    const float* __restrict__ scale, const float* __restrict__ shift) {
    __shared__ float As[64 * 132];   // pad 132: A-read 2-way conflict only (free)
    __shared__ float Ws[128 * 64];
    int t = threadIdx.x;
    int r0 = blockIdx.x * 64;
    int c0 = blockIdx.y * 64;
    // stage A tile 64x128 (2048 float4, 8/thread), fused BN+ReLU
    #pragma unroll
    for (int j = 0; j < 8; j++) {
        int idx = t + 256 * j;
        int row = idx >> 5;
        int colv = (idx & 31) << 2;
        float4 v;
        int gr = r0 + row;
        if (gr < NODES) v = *(const float4*)&A[gr * C + colv];
        else            v = make_float4(0.f, 0.f, 0.f, 0.f);
        if (scale) {
            float4 sc = *(const float4*)&scale[colv];
            float4 sh = *(const float4*)&shift[colv];
            v.x = fmaxf(0.f, fmaf(v.x, sc.x, sh.x));
            v.y = fmaxf(0.f, fmaf(v.y, sc.y, sh.y));
            v.z = fmaxf(0.f, fmaf(v.z, sc.z, sh.z));
            v.w = fmaxf(0.f, fmaf(v.w, sc.w, sh.w));
        }
        *(float4*)&As[row * 132 + colv] = v;
    }
    // stage W tile 128x64 (2048 float4, 8/thread)
    #pragma unroll
    for (int j = 0; j < 8; j++) {
        int idx = t + 256 * j;
        int row = idx >> 4;
        int colv = (idx & 15) << 2;
        *(float4*)&Ws[row * 64 + colv] = *(const float4*)&W[row * C + c0 + colv];
    }
    __syncthreads();
    int tx = t & 15, ty = t >> 4;
    float acc[4][4] = {};
    for (int k0 = 0; k0 < 128; k0 += 4) {
        float4 a[4];
        #pragma unroll
        for (int i = 0; i < 4; i++) a[i] = *(const float4*)&As[(ty * 4 + i) * 132 + k0];
        #pragma unroll
        for (int kk = 0; kk < 4; kk++) {
            float4 w = *(const float4*)&Ws[(k0 + kk) * 64 + tx * 4];
            #pragma unroll
            for (int i = 0; i < 4; i++) {
                float av = ((const float*)&a[i])[kk];
                acc[i][0] = fmaf(av, w.x, acc[i][0]);
                acc[i][1] = fmaf(av, w.y, acc[i][1]);
                acc[i][2] = fmaf(av, w.z, acc[i][2]);
                acc[i][3] = fmaf(av, w.w, acc[i][3]);
            }
        }
    }
    #pragma unroll
    for (int i = 0; i < 4; i++) {
        int gr = r0 + ty * 4 + i;
        if (gr < NODES) {
            float4 v = make_float4(acc[i][0], acc[i][1], acc[i][2], acc[i][3]);
            *(float4*)&Cm[gr * C + c0 + tx * 4] = v;
        }
    }
}

// ---------------- aggregation: one wave per node, gather-only via CSR ----------------
__global__ __launch_bounds__(256) void agg_kernel(
    const float* __restrict__ H, const int* __restrict__ rowptr,
    const int* __restrict__ col, const float* __restrict__ coef,
    float* __restrict__ Aout) {
    int wid = (blockIdx.x * 256 + threadIdx.x) >> 6;
    int lane = threadIdx.x & 63;
    if (wid >= NODES) return;
    int beg = rowptr[wid], end = rowptr[wid + 1];
    float2 acc = make_float2(0.f, 0.f);
    for (int i = beg; i < end; i++) {
        int s = col[i];
        float w = coef[i];
        float2 h = *(const float2*)&H[s * C + lane * 2];
        acc.x = fmaf(w, h.x, acc.x);
        acc.y = fmaf(w, h.y, acc.y);
    }
    *(float2*)&Aout[wid * C + lane * 2] = acc;
}

// ---------------- BN stats: per-channel sum & sumsq ----------------
__global__ __launch_bounds__(256) void stats_kernel(const float* __restrict__ X,
                                                    float* __restrict__ stats) {
    int t = threadIdx.x;
    int c = t & 127, half = t >> 7;
    float s = 0.f, q = 0.f;
    for (int row = blockIdx.x * 2 + half; row < NODES; row += gridDim.x * 2) {
        float v = X[row * C + c];
        s += v; q = fmaf(v, v, q);
    }
    __shared__ float red[512];
    red[t] = s; red[256 + t] = q;
    __syncthreads();
    if (half == 0) {
        s += red[t + 128]; q += red[256 + t + 128];
        atomicAdd(&stats[c], s);
        atomicAdd(&stats[128 + c], q);
    }
}

__global__ void finalize_kernel(const float* __restrict__ stats, const float* __restrict__ g,
                                const float* __restrict__ be, float* __restrict__ ss) {
    int c = threadIdx.x;  // 128
    float mean = stats[c] * (1.0f / NODES);
    float var = stats[128 + c] * (1.0f / NODES) - mean * mean;
    float sc = g[c] * rsqrtf(var + EPSBN);
    ss[c] = sc;
    ss[128 + c] = be[c] - mean * sc;
}

// ---------------- pooling ----------------
// batch is SORTED: per-graph counts via binary search, one thread per graph.
__global__ void bounds_kernel(const int* __restrict__ batch, int* __restrict__ pcnt) {
    int g = threadIdx.x;  // 64 threads
    if (g >= NGRAPH) return;
    // lower_bound for g and g+1
    int lo = 0, hi = NODES;
    while (lo < hi) { int m = (lo + hi) >> 1; if (batch[m] < g) lo = m + 1; else hi = m; }
    int s0 = lo;
    lo = 0; hi = NODES;
    int g1 = g + 1;
    while (lo < hi) { int m = (lo + hi) >> 1; if (batch[m] < g1) lo = m + 1; else hi = m; }
    pcnt[g] = lo - s0;
}

__global__ __launch_bounds__(128) void pool_kernel(const float* __restrict__ X,
                                                   const int* __restrict__ batch,
                                                   const float* __restrict__ ss,
                                                   float* __restrict__ psum) {
    int c = threadIdx.x;
    int r0 = blockIdx.x * 128;
    if (r0 >= NODES) return;
    int rend = min(r0 + 128, NODES);
    float sc = ss[c], sh = ss[128 + c];
    float acc = 0.f;
    int cur = batch[r0];
    for (int r = r0; r < rend; r++) {
        int g = batch[r];
        if (g != cur) { atomicAdd(&psum[cur * C + c], acc); acc = 0.f; cur = g; }
        float v = X[r * C + c];
        v = fmaxf(0.f, fmaf(v, sc, sh));
        acc += v;
    }
    atomicAdd(&psum[cur * C + c], acc);
}

__global__ void head_kernel(const float* __restrict__ psum, const int* __restrict__ pcnt,
                            const float* __restrict__ Wh, const float* __restrict__ bh,
                            float* __restrict__ out) {
    int t = threadIdx.x;  // 512
    int g = t >> 3, o = t & 7;
    float inv = 1.0f / fmaxf((float)pcnt[g], 1.0f);
    float acc = 0.f;
    for (int c = 0; c < C; c++) acc = fmaf(psum[g * C + c], Wh[c * 8 + o], acc);
    out[t] = fmaf(acc, inv, bh[o]);
}

extern "C" void kernel_launch(void* const* d_in, const int* in_sizes, int n_in,
                              void* d_out, int out_size, void* d_ws, size_t ws_size,
                              hipStream_t stream) {
    (void)in_sizes; (void)n_in; (void)out_size; (void)ws_size;
    const float* x    = (const float*)d_in[0];
    const int*   ei   = (const int*)d_in[1];      // [2, EDGES]: src then dst
    const int*   batch= (const int*)d_in[2];
    const float* W0   = (const float*)d_in[3];
    const float* g0   = (const float*)d_in[5];
    const float* be0  = (const float*)d_in[6];
    const float* W1   = (const float*)d_in[7];
    const float* g1   = (const float*)d_in[9];
    const float* be1  = (const float*)d_in[10];
    const float* W2   = (const float*)d_in[11];
    const float* g2   = (const float*)d_in[13];
    const float* be2  = (const float*)d_in[14];
    const float* Wh   = (const float*)d_in[15];
    const float* bh   = (const float*)d_in[16];
    float* out = (float*)d_out;

    char* ws = (char*)d_ws;
    int*   degcnt = (int*)(ws + OFF_DEGCNT);
    int*   cursor = (int*)(ws + OFF_CURSOR);
    float* stats  = (float*)(ws + OFF_STATS);
    float* psum   = (float*)(ws + OFF_PSUM);
    int*   pcnt   = (int*)(ws + OFF_PCNT);
    int*   rowptr = (int*)(ws + OFF_ROWPTR);
    float* dinv   = (float*)(ws + OFF_DINV);
    float* ss     = (float*)(ws + OFF_SS);
    int*   col    = (int*)(ws + OFF_COL);
    float* coef   = (float*)(ws + OFF_COEF);
    float* bufH   = (float*)(ws + OFF_BUFH);
    float* bufA   = (float*)(ws + OFF_BUFA);

    hipMemsetAsync(ws, 0, ZERO_BYTES, stream);

    const int EB = (EDGES + 255) / 256;
    deg_kernel<<<EB, 256, 0, stream>>>(ei + EDGES, degcnt);
    scan_kernel<<<1, 1024, 0, stream>>>(degcnt, rowptr, dinv);
    fill_kernel<<<EB, 256, 0, stream>>>(ei, ei + EDGES, rowptr, cursor, dinv, col, coef);

    dim3 gg((NODES + 63) / 64, 2);
    const int AGB = (NODES * 64 + 255) / 256;  // 12500

    // layer 0
    gemm_kernel<<<gg, 256, 0, stream>>>(x, W0, bufH, nullptr, nullptr);
    agg_kernel<<<AGB, 256, 0, stream>>>(bufH, rowptr, col, coef, bufA);
    stats_kernel<<<512, 256, 0, stream>>>(bufA, stats + 0);
    finalize_kernel<<<1, 128, 0, stream>>>(stats + 0, g0, be0, ss + 0);
    // layer 1 (BN0+ReLU fused into A-load)
    gemm_kernel<<<gg, 256, 0, stream>>>(bufA, W1, bufH, ss + 0, ss + 128);
    agg_kernel<<<AGB, 256, 0, stream>>>(bufH, rowptr, col, coef, bufA);
    stats_kernel<<<512, 256, 0, stream>>>(bufA, stats + 256);
    finalize_kernel<<<1, 128, 0, stream>>>(stats + 256, g1, be1, ss + 256);
    // layer 2
    gemm_kernel<<<gg, 256, 0, stream>>>(bufA, W2, bufH, ss + 256, ss + 384);
    agg_kernel<<<AGB, 256, 0, stream>>>(bufH, rowptr, col, coef, bufA);
    stats_kernel<<<512, 256, 0, stream>>>(bufA, stats + 512);
    finalize_kernel<<<1, 128, 0, stream>>>(stats + 512, g2, be2, ss + 512);
    // pool + head (BN2+ReLU fused into pool)
    bounds_kernel<<<1, 64, 0, stream>>>(batch, pcnt);
    pool_kernel<<<(NODES + 127) / 128, 128, 0, stream>>>(bufA, batch, ss + 512, psum);
    head_kernel<<<1, 512, 0, stream>>>(psum, pcnt, Wh, bh, out);
}

// Round 3
// 603.503 us; speedup vs baseline: 1.7142x; 1.1838x over previous
//
#include <hip/hip_runtime.h>

#define NODES 50000
#define EDGES 600000
#define C     128
#define NGRAPH 64
#define EPSBN 1e-5f
#define SCANB 196   // 196*256 = 50176 >= NODES

// ---------------- workspace layout (bytes) ----------------
// zeroed region (one hipMemsetAsync):
#define OFF_DEGCNT 0u          // int[50048]   -> 200192
#define OFF_CURSOR 200192u     // int[50048]   -> 400384
#define OFF_STATS  400384u     // float[768]   -> 403456
#define OFF_PSUM   403456u     // float[8192]  -> 436224
#define OFF_PCNT   436224u     // int[64]      -> 436480
#define ZERO_BYTES 436480u
// non-zeroed:
#define OFF_ROWPTR 436480u     // int[50056]   -> 636704
#define OFF_DINV   636704u     // float[50048] -> 836896
#define OFF_SS     836896u     // float[768]   -> 839968
#define OFF_BSUM   839968u     // int[256]     -> 840992
#define OFF_BOFF   840992u     // int[256]     -> 842016
#define OFF_COL    842016u     // int[600064]  -> 3242272
#define OFF_COEF   3242272u    // float[600064]-> 5642528
#define OFF_BUFH   5642528u    // float[6400000] -> 31242528
#define OFF_BUFA   31242528u   // float[6400000] -> 56842528

// ---------------- CSR build ----------------
__global__ void deg_kernel(const int* __restrict__ dst, int* __restrict__ degcnt) {
    int e = blockIdx.x * 256 + threadIdx.x;
    if (e < EDGES) atomicAdd(&degcnt[dst[e]], 1);
}

// phase 1: per-block sum of 256 deg entries
__global__ __launch_bounds__(256) void scan1_kernel(const int* __restrict__ degcnt,
                                                    int* __restrict__ bsum) {
    int t = threadIdx.x;
    int i = blockIdx.x * 256 + t;
    int v = (i < NODES) ? degcnt[i] : 0;
    __shared__ int sc[256];
    sc[t] = v; __syncthreads();
    for (int off = 128; off > 0; off >>= 1) {
        if (t < off) sc[t] += sc[t + off];
        __syncthreads();
    }
    if (t == 0) bsum[blockIdx.x] = sc[0];
}

// phase 2: exclusive scan of SCANB block sums (one block)
__global__ __launch_bounds__(256) void scan2_kernel(const int* __restrict__ bsum,
                                                    int* __restrict__ boff,
                                                    int* __restrict__ rowptr) {
    int t = threadIdx.x;
    int v = (t < SCANB) ? bsum[t] : 0;
    __shared__ int sc[256];
    sc[t] = v; __syncthreads();
    for (int off = 1; off < 256; off <<= 1) {
        int u = 0; if (t >= off) u = sc[t - off];
        __syncthreads(); sc[t] += u; __syncthreads();
    }
    if (t < SCANB) boff[t] = sc[t] - v;   // exclusive
    if (t == 0) rowptr[NODES] = EDGES;
}

// phase 3: block-local inclusive scan + offset; write rowptr & dinv
__global__ __launch_bounds__(256) void scan3_kernel(const int* __restrict__ degcnt,
                                                    const int* __restrict__ boff,
                                                    int* __restrict__ rowptr,
                                                    float* __restrict__ dinv) {
    int t = threadIdx.x;
    int i = blockIdx.x * 256 + t;
    int v = (i < NODES) ? degcnt[i] : 0;
    __shared__ int sc[256];
    sc[t] = v; __syncthreads();
    for (int off = 1; off < 256; off <<= 1) {
        int u = 0; if (t >= off) u = sc[t - off];
        __syncthreads(); sc[t] += u; __syncthreads();
    }
    if (i < NODES) {
        rowptr[i] = boff[blockIdx.x] + sc[t] - v;  // exclusive prefix
        dinv[i] = (v > 0) ? rsqrtf((float)v) : 0.f;
    }
}

__global__ void fill_kernel(const int* __restrict__ src, const int* __restrict__ dst,
                            const int* __restrict__ rowptr, int* __restrict__ cursor,
                            const float* __restrict__ dinv,
                            int* __restrict__ col, float* __restrict__ coef) {
    int e = blockIdx.x * 256 + threadIdx.x;
    if (e < EDGES) {
        int s = src[e], d = dst[e];
        int pos = rowptr[d] + atomicAdd(&cursor[d], 1);
        col[pos] = s;
        coef[pos] = dinv[s] * dinv[d];
    }
}

// ---------------- GEMM: [NODES,128] @ [128,64cols] with fused BN+ReLU on input ----------------
__global__ __launch_bounds__(256) void gemm_kernel(
    const float* __restrict__ A, const float* __restrict__ W, float* __restrict__ Cm,
    const float* __restrict__ scale, const float* __restrict__ shift) {
    __shared__ float As[64 * 132];
    __shared__ float Ws[128 * 64];
    int t = threadIdx.x;
    int r0 = blockIdx.x * 64;
    int c0 = blockIdx.y * 64;
    #pragma unroll
    for (int j = 0; j < 8; j++) {
        int idx = t + 256 * j;
        int row = idx >> 5;
        int colv = (idx & 31) << 2;
        float4 v;
        int gr = r0 + row;
        if (gr < NODES) v = *(const float4*)&A[gr * C + colv];
        else            v = make_float4(0.f, 0.f, 0.f, 0.f);
        if (scale) {
            float4 sc = *(const float4*)&scale[colv];
            float4 sh = *(const float4*)&shift[colv];
            v.x = fmaxf(0.f, fmaf(v.x, sc.x, sh.x));
            v.y = fmaxf(0.f, fmaf(v.y, sc.y, sh.y));
            v.z = fmaxf(0.f, fmaf(v.z, sc.z, sh.z));
            v.w = fmaxf(0.f, fmaf(v.w, sc.w, sh.w));
        }
        *(float4*)&As[row * 132 + colv] = v;
    }
    #pragma unroll
    for (int j = 0; j < 8; j++) {
        int idx = t + 256 * j;
        int row = idx >> 4;
        int colv = (idx & 15) << 2;
        *(float4*)&Ws[row * 64 + colv] = *(const float4*)&W[row * C + c0 + colv];
    }
    __syncthreads();
    int tx = t & 15, ty = t >> 4;
    float acc[4][4] = {};
    for (int k0 = 0; k0 < 128; k0 += 4) {
        float4 a[4];
        #pragma unroll
        for (int i = 0; i < 4; i++) a[i] = *(const float4*)&As[(ty * 4 + i) * 132 + k0];
        #pragma unroll
        for (int kk = 0; kk < 4; kk++) {
            float4 w = *(const float4*)&Ws[(k0 + kk) * 64 + tx * 4];
            #pragma unroll
            for (int i = 0; i < 4; i++) {
                float av = ((const float*)&a[i])[kk];
                acc[i][0] = fmaf(av, w.x, acc[i][0]);
                acc[i][1] = fmaf(av, w.y, acc[i][1]);
                acc[i][2] = fmaf(av, w.z, acc[i][2]);
                acc[i][3] = fmaf(av, w.w, acc[i][3]);
            }
        }
    }
    #pragma unroll
    for (int i = 0; i < 4; i++) {
        int gr = r0 + ty * 4 + i;
        if (gr < NODES) {
            float4 v = make_float4(acc[i][0], acc[i][1], acc[i][2], acc[i][3]);
            *(float4*)&Cm[gr * C + c0 + tx * 4] = v;
        }
    }
}

// ---------------- aggregation: one wave per node, gather-only via CSR ----------------
__global__ __launch_bounds__(256) void agg_kernel(
    const float* __restrict__ H, const int* __restrict__ rowptr,
    const int* __restrict__ col, const float* __restrict__ coef,
    float* __restrict__ Aout) {
    int wid = (blockIdx.x * 256 + threadIdx.x) >> 6;
    int lane = threadIdx.x & 63;
    if (wid >= NODES) return;
    int beg = rowptr[wid], end = rowptr[wid + 1];
    float2 acc = make_float2(0.f, 0.f);
    for (int i = beg; i < end; i++) {
        int s = col[i];
        float w = coef[i];
        float2 h = *(const float2*)&H[s * C + lane * 2];
        acc.x = fmaf(w, h.x, acc.x);
        acc.y = fmaf(w, h.y, acc.y);
    }
    *(float2*)&Aout[wid * C + lane * 2] = acc;
}

// ---------------- BN stats ----------------
__global__ __launch_bounds__(256) void stats_kernel(const float* __restrict__ X,
                                                    float* __restrict__ stats) {
    int t = threadIdx.x;
    int c = t & 127, half = t >> 7;
    float s = 0.f, q = 0.f;
    for (int row = blockIdx.x * 2 + half; row < NODES; row += gridDim.x * 2) {
        float v = X[row * C + c];
        s += v; q = fmaf(v, v, q);
    }
    __shared__ float red[512];
    red[t] = s; red[256 + t] = q;
    __syncthreads();
    if (half == 0) {
        s += red[t + 128]; q += red[256 + t + 128];
        atomicAdd(&stats[c], s);
        atomicAdd(&stats[128 + c], q);
    }
}

__global__ void finalize_kernel(const float* __restrict__ stats, const float* __restrict__ g,
                                const float* __restrict__ be, float* __restrict__ ss) {
    int c = threadIdx.x;  // 128
    float mean = stats[c] * (1.0f / NODES);
    float var = stats[128 + c] * (1.0f / NODES) - mean * mean;
    float sc = g[c] * rsqrtf(var + EPSBN);
    ss[c] = sc;
    ss[128 + c] = be[c] - mean * sc;
}

// ---------------- pooling ----------------
__global__ void bounds_kernel(const int* __restrict__ batch, int* __restrict__ pcnt) {
    int g = threadIdx.x;  // 64
    if (g >= NGRAPH) return;
    int lo = 0, hi = NODES;
    while (lo < hi) { int m = (lo + hi) >> 1; if (batch[m] < g) lo = m + 1; else hi = m; }
    int s0 = lo;
    lo = 0; hi = NODES;
    int g1 = g + 1;
    while (lo < hi) { int m = (lo + hi) >> 1; if (batch[m] < g1) lo = m + 1; else hi = m; }
    pcnt[g] = lo - s0;
}

__global__ __launch_bounds__(128) void pool_kernel(const float* __restrict__ X,
                                                   const int* __restrict__ batch,
                                                   const float* __restrict__ ss,
                                                   float* __restrict__ psum) {
    int c = threadIdx.x;
    int r0 = blockIdx.x * 128;
    if (r0 >= NODES) return;
    int rend = min(r0 + 128, NODES);
    float sc = ss[c], sh = ss[128 + c];
    float acc = 0.f;
    int cur = batch[r0];
    for (int r = r0; r < rend; r++) {
        int g = batch[r];
        if (g != cur) { atomicAdd(&psum[cur * C + c], acc); acc = 0.f; cur = g; }
        float v = X[r * C + c];
        v = fmaxf(0.f, fmaf(v, sc, sh));
        acc += v;
    }
    atomicAdd(&psum[cur * C + c], acc);
}

__global__ void head_kernel(const float* __restrict__ psum, const int* __restrict__ pcnt,
                            const float* __restrict__ Wh, const float* __restrict__ bh,
                            float* __restrict__ out) {
    int t = threadIdx.x;  // 512
    int g = t >> 3, o = t & 7;
    float inv = 1.0f / fmaxf((float)pcnt[g], 1.0f);
    float acc = 0.f;
    for (int c = 0; c < C; c++) acc = fmaf(psum[g * C + c], Wh[c * 8 + o], acc);
    out[t] = fmaf(acc, inv, bh[o]);
}

extern "C" void kernel_launch(void* const* d_in, const int* in_sizes, int n_in,
                              void* d_out, int out_size, void* d_ws, size_t ws_size,
                              hipStream_t stream) {
    (void)in_sizes; (void)n_in; (void)out_size; (void)ws_size;
    const float* x    = (const float*)d_in[0];
    const int*   ei   = (const int*)d_in[1];      // [2, EDGES]: src then dst
    const int*   batch= (const int*)d_in[2];
    const float* W0   = (const float*)d_in[3];
    const float* g0   = (const float*)d_in[5];
    const float* be0  = (const float*)d_in[6];
    const float* W1   = (const float*)d_in[7];
    const float* g1   = (const float*)d_in[9];
    const float* be1  = (const float*)d_in[10];
    const float* W2   = (const float*)d_in[11];
    const float* g2   = (const float*)d_in[13];
    const float* be2  = (const float*)d_in[14];
    const float* Wh   = (const float*)d_in[15];
    const float* bh   = (const float*)d_in[16];
    float* out = (float*)d_out;

    char* ws = (char*)d_ws;
    int*   degcnt = (int*)(ws + OFF_DEGCNT);
    int*   cursor = (int*)(ws + OFF_CURSOR);
    float* stats  = (float*)(ws + OFF_STATS);
    float* psum   = (float*)(ws + OFF_PSUM);
    int*   pcnt   = (int*)(ws + OFF_PCNT);
    int*   rowptr = (int*)(ws + OFF_ROWPTR);
    float* dinv   = (float*)(ws + OFF_DINV);
    float* ss     = (float*)(ws + OFF_SS);
    int*   bsum   = (int*)(ws + OFF_BSUM);
    int*   boff   = (int*)(ws + OFF_BOFF);
    int*   col    = (int*)(ws + OFF_COL);
    float* coef   = (float*)(ws + OFF_COEF);
    float* bufH   = (float*)(ws + OFF_BUFH);
    float* bufA   = (float*)(ws + OFF_BUFA);

    hipMemsetAsync(ws, 0, ZERO_BYTES, stream);

    const int EB = (EDGES + 255) / 256;
    deg_kernel<<<EB, 256, 0, stream>>>(ei + EDGES, degcnt);
    scan1_kernel<<<SCANB, 256, 0, stream>>>(degcnt, bsum);
    scan2_kernel<<<1, 256, 0, stream>>>(bsum, boff, rowptr);
    scan3_kernel<<<SCANB, 256, 0, stream>>>(degcnt, boff, rowptr, dinv);
    fill_kernel<<<EB, 256, 0, stream>>>(ei, ei + EDGES, rowptr, cursor, dinv, col, coef);

    dim3 gg((NODES + 63) / 64, 2);
    const int AGB = (NODES * 64 + 255) / 256;  // 12500

    // layer 0
    gemm_kernel<<<gg, 256, 0, stream>>>(x, W0, bufH, nullptr, nullptr);
    agg_kernel<<<AGB, 256, 0, stream>>>(bufH, rowptr, col, coef, bufA);
    stats_kernel<<<512, 256, 0, stream>>>(bufA, stats + 0);
    finalize_kernel<<<1, 128, 0, stream>>>(stats + 0, g0, be0, ss + 0);
    // layer 1 (BN0+ReLU fused into A-load)
    gemm_kernel<<<gg, 256, 0, stream>>>(bufA, W1, bufH, ss + 0, ss + 128);
    agg_kernel<<<AGB, 256, 0, stream>>>(bufH, rowptr, col, coef, bufA);
    stats_kernel<<<512, 256, 0, stream>>>(bufA, stats + 256);
    finalize_kernel<<<1, 128, 0, stream>>>(stats + 256, g1, be1, ss + 256);
    // layer 2
    gemm_kernel<<<gg, 256, 0, stream>>>(bufA, W2, bufH, ss + 256, ss + 384);
    agg_kernel<<<AGB, 256, 0, stream>>>(bufH, rowptr, col, coef, bufA);
    stats_kernel<<<512, 256, 0, stream>>>(bufA, stats + 512);
    finalize_kernel<<<1, 128, 0, stream>>>(stats + 512, g2, be2, ss + 512);
    // pool + head (BN2+ReLU fused into pool)
    bounds_kernel<<<1, 64, 0, stream>>>(batch, pcnt);
    pool_kernel<<<(NODES + 127) / 128, 128, 0, stream>>>(bufA, batch, ss + 512, psum);
    head_kernel<<<1, 512, 0, stream>>>(psum, pcnt, Wh, bh, out);
}

// Round 4
// 552.999 us; speedup vs baseline: 1.8707x; 1.0913x over previous
//
#include <hip/hip_runtime.h>

#define NODES 50000
#define EDGES 600000
#define C     128
#define NGRAPH 64
#define EPSBN 1e-5f
#define SCANB 196   // 196*256 = 50176 >= NODES

// ---------------- workspace layout (bytes) ----------------
// zeroed region (one hipMemsetAsync):
#define OFF_DEGCNT 0u          // int[50048]   -> 200192
#define OFF_CURSOR 200192u     // int[50048]   -> 400384
#define OFF_STATS  400384u     // float[768]   -> 403456
#define OFF_PSUM   403456u     // float[8192]  -> 436224
#define OFF_PCNT   436224u     // int[64]      -> 436480
#define ZERO_BYTES 436480u
// non-zeroed:
#define OFF_ROWPTR 436480u     // int[50056]   -> 636704
#define OFF_DINV   636704u     // float[50048] -> 836896
#define OFF_SS     836896u     // float[768]   -> 839968
#define OFF_BSUM   839968u     // int[256]     -> 840992
#define OFF_BOFF   840992u     // int[256]     -> 842016
#define OFF_COL    842016u     // int[600064]  -> 3242272
#define OFF_COEF   3242272u    // float[600064]-> 5642528
#define OFF_BUFH   5642528u    // float[6400000] -> 31242528
#define OFF_BUFA   31242528u   // float[6400000] -> 56842528

// ---------------- CSR build ----------------
__global__ void deg_kernel(const int* __restrict__ dst, int* __restrict__ degcnt) {
    int e = blockIdx.x * 256 + threadIdx.x;
    if (e < EDGES) atomicAdd(&degcnt[dst[e]], 1);
}

// phase 1: per-block sum of 256 deg entries
__global__ __launch_bounds__(256) void scan1_kernel(const int* __restrict__ degcnt,
                                                    int* __restrict__ bsum) {
    int t = threadIdx.x;
    int i = blockIdx.x * 256 + t;
    int v = (i < NODES) ? degcnt[i] : 0;
    __shared__ int sc[256];
    sc[t] = v; __syncthreads();
    for (int off = 128; off > 0; off >>= 1) {
        if (t < off) sc[t] += sc[t + off];
        __syncthreads();
    }
    if (t == 0) bsum[blockIdx.x] = sc[0];
}

// phase 2: exclusive scan of SCANB block sums (one block)
__global__ __launch_bounds__(256) void scan2_kernel(const int* __restrict__ bsum,
                                                    int* __restrict__ boff,
                                                    int* __restrict__ rowptr) {
    int t = threadIdx.x;
    int v = (t < SCANB) ? bsum[t] : 0;
    __shared__ int sc[256];
    sc[t] = v; __syncthreads();
    for (int off = 1; off < 256; off <<= 1) {
        int u = 0; if (t >= off) u = sc[t - off];
        __syncthreads(); sc[t] += u; __syncthreads();
    }
    if (t < SCANB) boff[t] = sc[t] - v;   // exclusive
    if (t == 0) rowptr[NODES] = EDGES;
}

// phase 3: block-local inclusive scan + offset; write rowptr & dinv
__global__ __launch_bounds__(256) void scan3_kernel(const int* __restrict__ degcnt,
                                                    const int* __restrict__ boff,
                                                    int* __restrict__ rowptr,
                                                    float* __restrict__ dinv) {
    int t = threadIdx.x;
    int i = blockIdx.x * 256 + t;
    int v = (i < NODES) ? degcnt[i] : 0;
    __shared__ int sc[256];
    sc[t] = v; __syncthreads();
    for (int off = 1; off < 256; off <<= 1) {
        int u = 0; if (t >= off) u = sc[t - off];
        __syncthreads(); sc[t] += u; __syncthreads();
    }
    if (i < NODES) {
        rowptr[i] = boff[blockIdx.x] + sc[t] - v;  // exclusive prefix
        dinv[i] = (v > 0) ? rsqrtf((float)v) : 0.f;
    }
}

__global__ void fill_kernel(const int* __restrict__ src, const int* __restrict__ dst,
                            const int* __restrict__ rowptr, int* __restrict__ cursor,
                            const float* __restrict__ dinv,
                            int* __restrict__ col, float* __restrict__ coef) {
    int e = blockIdx.x * 256 + threadIdx.x;
    if (e < EDGES) {
        int s = src[e], d = dst[e];
        int pos = rowptr[d] + atomicAdd(&cursor[d], 1);
        col[pos] = s;
        coef[pos] = dinv[s] * dinv[d];
    }
}

// ---------------- GEMM: [NODES,128] @ [128,64cols] with fused BN+ReLU on input ----------------
__global__ __launch_bounds__(256) void gemm_kernel(
    const float* __restrict__ A, const float* __restrict__ W, float* __restrict__ Cm,
    const float* __restrict__ scale, const float* __restrict__ shift) {
    __shared__ float As[64 * 132];
    __shared__ float Ws[128 * 64];
    int t = threadIdx.x;
    int r0 = blockIdx.x * 64;
    int c0 = blockIdx.y * 64;
    #pragma unroll
    for (int j = 0; j < 8; j++) {
        int idx = t + 256 * j;
        int row = idx >> 5;
        int colv = (idx & 31) << 2;
        float4 v;
        int gr = r0 + row;
        if (gr < NODES) v = *(const float4*)&A[gr * C + colv];
        else            v = make_float4(0.f, 0.f, 0.f, 0.f);
        if (scale) {
            float4 sc = *(const float4*)&scale[colv];
            float4 sh = *(const float4*)&shift[colv];
            v.x = fmaxf(0.f, fmaf(v.x, sc.x, sh.x));
            v.y = fmaxf(0.f, fmaf(v.y, sc.y, sh.y));
            v.z = fmaxf(0.f, fmaf(v.z, sc.z, sh.z));
            v.w = fmaxf(0.f, fmaf(v.w, sc.w, sh.w));
        }
        *(float4*)&As[row * 132 + colv] = v;
    }
    #pragma unroll
    for (int j = 0; j < 8; j++) {
        int idx = t + 256 * j;
        int row = idx >> 4;
        int colv = (idx & 15) << 2;
        *(float4*)&Ws[row * 64 + colv] = *(const float4*)&W[row * C + c0 + colv];
    }
    __syncthreads();
    int tx = t & 15, ty = t >> 4;
    float acc[4][4] = {};
    for (int k0 = 0; k0 < 128; k0 += 4) {
        float4 a[4];
        #pragma unroll
        for (int i = 0; i < 4; i++) a[i] = *(const float4*)&As[(ty * 4 + i) * 132 + k0];
        #pragma unroll
        for (int kk = 0; kk < 4; kk++) {
            float4 w = *(const float4*)&Ws[(k0 + kk) * 64 + tx * 4];
            #pragma unroll
            for (int i = 0; i < 4; i++) {
                float av = ((const float*)&a[i])[kk];
                acc[i][0] = fmaf(av, w.x, acc[i][0]);
                acc[i][1] = fmaf(av, w.y, acc[i][1]);
                acc[i][2] = fmaf(av, w.z, acc[i][2]);
                acc[i][3] = fmaf(av, w.w, acc[i][3]);
            }
        }
    }
    #pragma unroll
    for (int i = 0; i < 4; i++) {
        int gr = r0 + ty * 4 + i;
        if (gr < NODES) {
            float4 v = make_float4(acc[i][0], acc[i][1], acc[i][2], acc[i][3]);
            *(float4*)&Cm[gr * C + c0 + tx * 4] = v;
        }
    }
}

// ---------------- aggregation: one wave per node, CSR gather, 4-way MLP unroll ----------------
__global__ __launch_bounds__(256) void agg_kernel(
    const float* __restrict__ H, const int* __restrict__ rowptr,
    const int* __restrict__ col, const float* __restrict__ coef,
    float* __restrict__ Aout) {
    int wid = (blockIdx.x * 256 + threadIdx.x) >> 6;
    int lane = threadIdx.x & 63;
    if (wid >= NODES) return;
    int beg = rowptr[wid], end = rowptr[wid + 1];
    const float* Hl = H + lane * 2;
    float2 acc = make_float2(0.f, 0.f);
    int i = beg;
    // main: 4 independent 512-B row fetches in flight per wave
    for (; i + 4 <= end; i += 4) {
        int s0 = col[i], s1 = col[i + 1], s2 = col[i + 2], s3 = col[i + 3];
        float w0 = coef[i], w1 = coef[i + 1], w2 = coef[i + 2], w3 = coef[i + 3];
        float2 h0 = *(const float2*)&Hl[s0 * C];
        float2 h1 = *(const float2*)&Hl[s1 * C];
        float2 h2 = *(const float2*)&Hl[s2 * C];
        float2 h3 = *(const float2*)&Hl[s3 * C];
        acc.x = fmaf(w0, h0.x, acc.x); acc.y = fmaf(w0, h0.y, acc.y);
        acc.x = fmaf(w1, h1.x, acc.x); acc.y = fmaf(w1, h1.y, acc.y);
        acc.x = fmaf(w2, h2.x, acc.x); acc.y = fmaf(w2, h2.y, acc.y);
        acc.x = fmaf(w3, h3.x, acc.x); acc.y = fmaf(w3, h3.y, acc.y);
    }
    for (; i < end; i++) {
        int s0 = col[i];
        float w0 = coef[i];
        float2 h0 = *(const float2*)&Hl[s0 * C];
        acc.x = fmaf(w0, h0.x, acc.x); acc.y = fmaf(w0, h0.y, acc.y);
    }
    *(float2*)&Aout[wid * C + lane * 2] = acc;
}

// ---------------- BN stats ----------------
__global__ __launch_bounds__(256) void stats_kernel(const float* __restrict__ X,
                                                    float* __restrict__ stats) {
    int t = threadIdx.x;
    int c = t & 127, half = t >> 7;
    float s = 0.f, q = 0.f;
    for (int row = blockIdx.x * 2 + half; row < NODES; row += gridDim.x * 2) {
        float v = X[row * C + c];
        s += v; q = fmaf(v, v, q);
    }
    __shared__ float red[512];
    red[t] = s; red[256 + t] = q;
    __syncthreads();
    if (half == 0) {
        s += red[t + 128]; q += red[256 + t + 128];
        atomicAdd(&stats[c], s);
        atomicAdd(&stats[128 + c], q);
    }
}

__global__ void finalize_kernel(const float* __restrict__ stats, const float* __restrict__ g,
                                const float* __restrict__ be, float* __restrict__ ss) {
    int c = threadIdx.x;  // 128
    float mean = stats[c] * (1.0f / NODES);
    float var = stats[128 + c] * (1.0f / NODES) - mean * mean;
    float sc = g[c] * rsqrtf(var + EPSBN);
    ss[c] = sc;
    ss[128 + c] = be[c] - mean * sc;
}

// ---------------- pooling ----------------
__global__ void bounds_kernel(const int* __restrict__ batch, int* __restrict__ pcnt) {
    int g = threadIdx.x;  // 64
    if (g >= NGRAPH) return;
    int lo = 0, hi = NODES;
    while (lo < hi) { int m = (lo + hi) >> 1; if (batch[m] < g) lo = m + 1; else hi = m; }
    int s0 = lo;
    lo = 0; hi = NODES;
    int g1 = g + 1;
    while (lo < hi) { int m = (lo + hi) >> 1; if (batch[m] < g1) lo = m + 1; else hi = m; }
    pcnt[g] = lo - s0;
}

__global__ __launch_bounds__(128) void pool_kernel(const float* __restrict__ X,
                                                   const int* __restrict__ batch,
                                                   const float* __restrict__ ss,
                                                   float* __restrict__ psum) {
    int c = threadIdx.x;
    int r0 = blockIdx.x * 128;
    if (r0 >= NODES) return;
    int rend = min(r0 + 128, NODES);
    float sc = ss[c], sh = ss[128 + c];
    float acc = 0.f;
    int cur = batch[r0];
    for (int r = r0; r < rend; r++) {
        int g = batch[r];
        if (g != cur) { atomicAdd(&psum[cur * C + c], acc); acc = 0.f; cur = g; }
        float v = X[r * C + c];
        v = fmaxf(0.f, fmaf(v, sc, sh));
        acc += v;
    }
    atomicAdd(&psum[cur * C + c], acc);
}

__global__ void head_kernel(const float* __restrict__ psum, const int* __restrict__ pcnt,
                            const float* __restrict__ Wh, const float* __restrict__ bh,
                            float* __restrict__ out) {
    int t = threadIdx.x;  // 512
    int g = t >> 3, o = t & 7;
    float inv = 1.0f / fmaxf((float)pcnt[g], 1.0f);
    float acc = 0.f;
    for (int c = 0; c < C; c++) acc = fmaf(psum[g * C + c], Wh[c * 8 + o], acc);
    out[t] = fmaf(acc, inv, bh[o]);
}

extern "C" void kernel_launch(void* const* d_in, const int* in_sizes, int n_in,
                              void* d_out, int out_size, void* d_ws, size_t ws_size,
                              hipStream_t stream) {
    (void)in_sizes; (void)n_in; (void)out_size; (void)ws_size;
    const float* x    = (const float*)d_in[0];
    const int*   ei   = (const int*)d_in[1];      // [2, EDGES]: src then dst
    const int*   batch= (const int*)d_in[2];
    const float* W0   = (const float*)d_in[3];
    const float* g0   = (const float*)d_in[5];
    const float* be0  = (const float*)d_in[6];
    const float* W1   = (const float*)d_in[7];
    const float* g1   = (const float*)d_in[9];
    const float* be1  = (const float*)d_in[10];
    const float* W2   = (const float*)d_in[11];
    const float* g2   = (const float*)d_in[13];
    const float* be2  = (const float*)d_in[14];
    const float* Wh   = (const float*)d_in[15];
    const float* bh   = (const float*)d_in[16];
    float* out = (float*)d_out;

    char* ws = (char*)d_ws;
    int*   degcnt = (int*)(ws + OFF_DEGCNT);
    int*   cursor = (int*)(ws + OFF_CURSOR);
    float* stats  = (float*)(ws + OFF_STATS);
    float* psum   = (float*)(ws + OFF_PSUM);
    int*   pcnt   = (int*)(ws + OFF_PCNT);
    int*   rowptr = (int*)(ws + OFF_ROWPTR);
    float* dinv   = (float*)(ws + OFF_DINV);
    float* ss     = (float*)(ws + OFF_SS);
    int*   bsum   = (int*)(ws + OFF_BSUM);
    int*   boff   = (int*)(ws + OFF_BOFF);
    int*   col    = (int*)(ws + OFF_COL);
    float* coef   = (float*)(ws + OFF_COEF);
    float* bufH   = (float*)(ws + OFF_BUFH);
    float* bufA   = (float*)(ws + OFF_BUFA);

    hipMemsetAsync(ws, 0, ZERO_BYTES, stream);

    const int EB = (EDGES + 255) / 256;
    deg_kernel<<<EB, 256, 0, stream>>>(ei + EDGES, degcnt);
    scan1_kernel<<<SCANB, 256, 0, stream>>>(degcnt, bsum);
    scan2_kernel<<<1, 256, 0, stream>>>(bsum, boff, rowptr);
    scan3_kernel<<<SCANB, 256, 0, stream>>>(degcnt, boff, rowptr, dinv);
    fill_kernel<<<EB, 256, 0, stream>>>(ei, ei + EDGES, rowptr, cursor, dinv, col, coef);

    dim3 gg((NODES + 63) / 64, 2);
    const int AGB = (NODES * 64 + 255) / 256;  // 12500

    // layer 0
    gemm_kernel<<<gg, 256, 0, stream>>>(x, W0, bufH, nullptr, nullptr);
    agg_kernel<<<AGB, 256, 0, stream>>>(bufH, rowptr, col, coef, bufA);
    stats_kernel<<<512, 256, 0, stream>>>(bufA, stats + 0);
    finalize_kernel<<<1, 128, 0, stream>>>(stats + 0, g0, be0, ss + 0);
    // layer 1 (BN0+ReLU fused into A-load)
    gemm_kernel<<<gg, 256, 0, stream>>>(bufA, W1, bufH, ss + 0, ss + 128);
    agg_kernel<<<AGB, 256, 0, stream>>>(bufH, rowptr, col, coef, bufA);
    stats_kernel<<<512, 256, 0, stream>>>(bufA, stats + 256);
    finalize_kernel<<<1, 128, 0, stream>>>(stats + 256, g1, be1, ss + 256);
    // layer 2
    gemm_kernel<<<gg, 256, 0, stream>>>(bufA, W2, bufH, ss + 256, ss + 384);
    agg_kernel<<<AGB, 256, 0, stream>>>(bufH, rowptr, col, coef, bufA);
    stats_kernel<<<512, 256, 0, stream>>>(bufA, stats + 512);
    finalize_kernel<<<1, 128, 0, stream>>>(stats + 512, g2, be2, ss + 512);
    // pool + head (BN2+ReLU fused into pool)
    bounds_kernel<<<1, 64, 0, stream>>>(batch, pcnt);
    pool_kernel<<<(NODES + 127) / 128, 128, 0, stream>>>(bufA, batch, ss + 512, psum);
    head_kernel<<<1, 512, 0, stream>>>(psum, pcnt, Wh, bh, out);
}

// Round 5
// 490.145 us; speedup vs baseline: 2.1106x; 1.1282x over previous
//
#include <hip/hip_runtime.h>

#define NODES 50000
#define EDGES 600000
#define C     128
#define NGRAPH 64
#define EPSBN 1e-5f
#define SCANB 196   // 196*256 = 50176 >= NODES

// ---------------- workspace layout (bytes) ----------------
// zeroed region (one hipMemsetAsync):
#define OFF_DEGCNT 0u          // int[50048]   -> 200192
#define OFF_CURSOR 200192u     // int[50048]   -> 400384
#define OFF_STATS  400384u     // float[768]   -> 403456
#define OFF_PSUM   403456u     // float[8192]  -> 436224
#define OFF_PCNT   436224u     // int[64]      -> 436480
#define ZERO_BYTES 436480u
// non-zeroed:
#define OFF_ROWPTR 436480u     // int[50056]   -> 636704
#define OFF_DINV   636704u     // float[50048] -> 836896
#define OFF_SS     836896u     // float[768]   -> 839968
#define OFF_BSUM   839968u     // int[256]     -> 840992
#define OFF_BOFF   840992u     // int[256]     -> 842016
#define OFF_COL    842016u     // int[600064]  -> 3242272
#define OFF_COEF   3242272u    // float[600064]-> 5642528
#define OFF_BUFH   5642528u    // ushort[6400000] (bf16 H) -> 18442528
#define OFF_BUFA   18442528u   // float[6400000] -> 44042528

// fp32 -> bf16 round-to-nearest-even
static __device__ __forceinline__ unsigned short f2bf(float f) {
    unsigned u = __float_as_uint(f);
    u += 0x7fffu + ((u >> 16) & 1u);
    return (unsigned short)(u >> 16);
}

// ---------------- CSR build ----------------
__global__ void deg_kernel(const int* __restrict__ dst, int* __restrict__ degcnt) {
    int e = blockIdx.x * 256 + threadIdx.x;
    if (e < EDGES) atomicAdd(&degcnt[dst[e]], 1);
}

__global__ __launch_bounds__(256) void scan1_kernel(const int* __restrict__ degcnt,
                                                    int* __restrict__ bsum) {
    int t = threadIdx.x;
    int i = blockIdx.x * 256 + t;
    int v = (i < NODES) ? degcnt[i] : 0;
    __shared__ int sc[256];
    sc[t] = v; __syncthreads();
    for (int off = 128; off > 0; off >>= 1) {
        if (t < off) sc[t] += sc[t + off];
        __syncthreads();
    }
    if (t == 0) bsum[blockIdx.x] = sc[0];
}

__global__ __launch_bounds__(256) void scan2_kernel(const int* __restrict__ bsum,
                                                    int* __restrict__ boff,
                                                    int* __restrict__ rowptr) {
    int t = threadIdx.x;
    int v = (t < SCANB) ? bsum[t] : 0;
    __shared__ int sc[256];
    sc[t] = v; __syncthreads();
    for (int off = 1; off < 256; off <<= 1) {
        int u = 0; if (t >= off) u = sc[t - off];
        __syncthreads(); sc[t] += u; __syncthreads();
    }
    if (t < SCANB) boff[t] = sc[t] - v;   // exclusive
    if (t == 0) rowptr[NODES] = EDGES;
}

__global__ __launch_bounds__(256) void scan3_kernel(const int* __restrict__ degcnt,
                                                    const int* __restrict__ boff,
                                                    int* __restrict__ rowptr,
                                                    float* __restrict__ dinv) {
    int t = threadIdx.x;
    int i = blockIdx.x * 256 + t;
    int v = (i < NODES) ? degcnt[i] : 0;
    __shared__ int sc[256];
    sc[t] = v; __syncthreads();
    for (int off = 1; off < 256; off <<= 1) {
        int u = 0; if (t >= off) u = sc[t - off];
        __syncthreads(); sc[t] += u; __syncthreads();
    }
    if (i < NODES) {
        rowptr[i] = boff[blockIdx.x] + sc[t] - v;  // exclusive prefix
        dinv[i] = (v > 0) ? rsqrtf((float)v) : 0.f;
    }
}

__global__ void fill_kernel(const int* __restrict__ src, const int* __restrict__ dst,
                            const int* __restrict__ rowptr, int* __restrict__ cursor,
                            const float* __restrict__ dinv,
                            int* __restrict__ col, float* __restrict__ coef) {
    int e = blockIdx.x * 256 + threadIdx.x;
    if (e < EDGES) {
        int s = src[e], d = dst[e];
        int pos = rowptr[d] + atomicAdd(&cursor[d], 1);
        col[pos] = s;
        coef[pos] = dinv[s] * dinv[d];
    }
}

// ---------------- GEMM: [NODES,128] @ [128,64cols], fused BN+ReLU input, bf16 output ---------
__global__ __launch_bounds__(256) void gemm_kernel(
    const float* __restrict__ A, const float* __restrict__ W, unsigned short* __restrict__ Cm,
    const float* __restrict__ scale, const float* __restrict__ shift) {
    __shared__ float As[64 * 132];
    __shared__ float Ws[128 * 64];
    int t = threadIdx.x;
    int r0 = blockIdx.x * 64;
    int c0 = blockIdx.y * 64;
    #pragma unroll
    for (int j = 0; j < 8; j++) {
        int idx = t + 256 * j;
        int row = idx >> 5;
        int colv = (idx & 31) << 2;
        float4 v;
        int gr = r0 + row;
        if (gr < NODES) v = *(const float4*)&A[gr * C + colv];
        else            v = make_float4(0.f, 0.f, 0.f, 0.f);
        if (scale) {
            float4 sc = *(const float4*)&scale[colv];
            float4 sh = *(const float4*)&shift[colv];
            v.x = fmaxf(0.f, fmaf(v.x, sc.x, sh.x));
            v.y = fmaxf(0.f, fmaf(v.y, sc.y, sh.y));
            v.z = fmaxf(0.f, fmaf(v.z, sc.z, sh.z));
            v.w = fmaxf(0.f, fmaf(v.w, sc.w, sh.w));
        }
        *(float4*)&As[row * 132 + colv] = v;
    }
    #pragma unroll
    for (int j = 0; j < 8; j++) {
        int idx = t + 256 * j;
        int row = idx >> 4;
        int colv = (idx & 15) << 2;
        *(float4*)&Ws[row * 64 + colv] = *(const float4*)&W[row * C + c0 + colv];
    }
    __syncthreads();
    int tx = t & 15, ty = t >> 4;
    float acc[4][4] = {};
    for (int k0 = 0; k0 < 128; k0 += 4) {
        float4 a[4];
        #pragma unroll
        for (int i = 0; i < 4; i++) a[i] = *(const float4*)&As[(ty * 4 + i) * 132 + k0];
        #pragma unroll
        for (int kk = 0; kk < 4; kk++) {
            float4 w = *(const float4*)&Ws[(k0 + kk) * 64 + tx * 4];
            #pragma unroll
            for (int i = 0; i < 4; i++) {
                float av = ((const float*)&a[i])[kk];
                acc[i][0] = fmaf(av, w.x, acc[i][0]);
                acc[i][1] = fmaf(av, w.y, acc[i][1]);
                acc[i][2] = fmaf(av, w.z, acc[i][2]);
                acc[i][3] = fmaf(av, w.w, acc[i][3]);
            }
        }
    }
    #pragma unroll
    for (int i = 0; i < 4; i++) {
        int gr = r0 + ty * 4 + i;
        if (gr < NODES) {
            ushort4 o;
            o.x = f2bf(acc[i][0]); o.y = f2bf(acc[i][1]);
            o.z = f2bf(acc[i][2]); o.w = f2bf(acc[i][3]);
            *(ushort4*)&Cm[gr * C + c0 + tx * 4] = o;
        }
    }
}

// ---------------- aggregation: wave/node, bf16 gather, 8-way MLP unroll ----------------
static __device__ __forceinline__ void bf2f2(unsigned u, float& x, float& y) {
    x = __uint_as_float(u << 16);
    y = __uint_as_float(u & 0xffff0000u);
}

__global__ __launch_bounds__(256) void agg_kernel(
    const unsigned short* __restrict__ H, const int* __restrict__ rowptr,
    const int* __restrict__ col, const float* __restrict__ coef,
    float* __restrict__ Aout) {
    int wid = (blockIdx.x * 256 + threadIdx.x) >> 6;
    int lane = threadIdx.x & 63;
    if (wid >= NODES) return;
    int beg = rowptr[wid], end = rowptr[wid + 1];
    const unsigned short* Hl = H + lane * 2;
    float ax = 0.f, ay = 0.f;
    int i = beg;
    for (; i + 8 <= end; i += 8) {
        int s[8]; float w[8]; unsigned u[8];
        #pragma unroll
        for (int j = 0; j < 8; j++) s[j] = col[i + j];
        #pragma unroll
        for (int j = 0; j < 8; j++) w[j] = coef[i + j];
        #pragma unroll
        for (int j = 0; j < 8; j++) u[j] = *(const unsigned*)&Hl[s[j] * C];
        #pragma unroll
        for (int j = 0; j < 8; j++) {
            float hx, hy; bf2f2(u[j], hx, hy);
            ax = fmaf(w[j], hx, ax); ay = fmaf(w[j], hy, ay);
        }
    }
    for (; i + 4 <= end; i += 4) {
        int s[4]; float w[4]; unsigned u[4];
        #pragma unroll
        for (int j = 0; j < 4; j++) s[j] = col[i + j];
        #pragma unroll
        for (int j = 0; j < 4; j++) w[j] = coef[i + j];
        #pragma unroll
        for (int j = 0; j < 4; j++) u[j] = *(const unsigned*)&Hl[s[j] * C];
        #pragma unroll
        for (int j = 0; j < 4; j++) {
            float hx, hy; bf2f2(u[j], hx, hy);
            ax = fmaf(w[j], hx, ax); ay = fmaf(w[j], hy, ay);
        }
    }
    for (; i < end; i++) {
        int s0 = col[i];
        float w0 = coef[i];
        float hx, hy; bf2f2(*(const unsigned*)&Hl[s0 * C], hx, hy);
        ax = fmaf(w0, hx, ax); ay = fmaf(w0, hy, ay);
    }
    *(float2*)&Aout[wid * C + lane * 2] = make_float2(ax, ay);
}

// ---------------- BN stats ----------------
__global__ __launch_bounds__(256) void stats_kernel(const float* __restrict__ X,
                                                    float* __restrict__ stats) {
    int t = threadIdx.x;
    int c = t & 127, half = t >> 7;
    float s = 0.f, q = 0.f;
    for (int row = blockIdx.x * 2 + half; row < NODES; row += gridDim.x * 2) {
        float v = X[row * C + c];
        s += v; q = fmaf(v, v, q);
    }
    __shared__ float red[512];
    red[t] = s; red[256 + t] = q;
    __syncthreads();
    if (half == 0) {
        s += red[t + 128]; q += red[256 + t + 128];
        atomicAdd(&stats[c], s);
        atomicAdd(&stats[128 + c], q);
    }
}

__global__ void finalize_kernel(const float* __restrict__ stats, const float* __restrict__ g,
                                const float* __restrict__ be, float* __restrict__ ss) {
    int c = threadIdx.x;  // 128
    float mean = stats[c] * (1.0f / NODES);
    float var = stats[128 + c] * (1.0f / NODES) - mean * mean;
    float sc = g[c] * rsqrtf(var + EPSBN);
    ss[c] = sc;
    ss[128 + c] = be[c] - mean * sc;
}

// ---------------- pooling ----------------
__global__ void bounds_kernel(const int* __restrict__ batch, int* __restrict__ pcnt) {
    int g = threadIdx.x;  // 64
    if (g >= NGRAPH) return;
    int lo = 0, hi = NODES;
    while (lo < hi) { int m = (lo + hi) >> 1; if (batch[m] < g) lo = m + 1; else hi = m; }
    int s0 = lo;
    lo = 0; hi = NODES;
    int g1 = g + 1;
    while (lo < hi) { int m = (lo + hi) >> 1; if (batch[m] < g1) lo = m + 1; else hi = m; }
    pcnt[g] = lo - s0;
}

__global__ __launch_bounds__(128) void pool_kernel(const float* __restrict__ X,
                                                   const int* __restrict__ batch,
                                                   const float* __restrict__ ss,
                                                   float* __restrict__ psum) {
    int c = threadIdx.x;
    int r0 = blockIdx.x * 128;
    if (r0 >= NODES) return;
    int rend = min(r0 + 128, NODES);
    float sc = ss[c], sh = ss[128 + c];
    float acc = 0.f;
    int cur = batch[r0];
    for (int r = r0; r < rend; r++) {
        int g = batch[r];
        if (g != cur) { atomicAdd(&psum[cur * C + c], acc); acc = 0.f; cur = g; }
        float v = X[r * C + c];
        v = fmaxf(0.f, fmaf(v, sc, sh));
        acc += v;
    }
    atomicAdd(&psum[cur * C + c], acc);
}

__global__ void head_kernel(const float* __restrict__ psum, const int* __restrict__ pcnt,
                            const float* __restrict__ Wh, const float* __restrict__ bh,
                            float* __restrict__ out) {
    int t = threadIdx.x;  // 512
    int g = t >> 3, o = t & 7;
    float inv = 1.0f / fmaxf((float)pcnt[g], 1.0f);
    float acc = 0.f;
    for (int c = 0; c < C; c++) acc = fmaf(psum[g * C + c], Wh[c * 8 + o], acc);
    out[t] = fmaf(acc, inv, bh[o]);
}

extern "C" void kernel_launch(void* const* d_in, const int* in_sizes, int n_in,
                              void* d_out, int out_size, void* d_ws, size_t ws_size,
                              hipStream_t stream) {
    (void)in_sizes; (void)n_in; (void)out_size; (void)ws_size;
    const float* x    = (const float*)d_in[0];
    const int*   ei   = (const int*)d_in[1];      // [2, EDGES]: src then dst
    const int*   batch= (const int*)d_in[2];
    const float* W0   = (const float*)d_in[3];
    const float* g0   = (const float*)d_in[5];
    const float* be0  = (const float*)d_in[6];
    const float* W1   = (const float*)d_in[7];
    const float* g1   = (const float*)d_in[9];
    const float* be1  = (const float*)d_in[10];
    const float* W2   = (const float*)d_in[11];
    const float* g2   = (const float*)d_in[13];
    const float* be2  = (const float*)d_in[14];
    const float* Wh   = (const float*)d_in[15];
    const float* bh   = (const float*)d_in[16];
    float* out = (float*)d_out;

    char* ws = (char*)d_ws;
    int*   degcnt = (int*)(ws + OFF_DEGCNT);
    int*   cursor = (int*)(ws + OFF_CURSOR);
    float* stats  = (float*)(ws + OFF_STATS);
    float* psum   = (float*)(ws + OFF_PSUM);
    int*   pcnt   = (int*)(ws + OFF_PCNT);
    int*   rowptr = (int*)(ws + OFF_ROWPTR);
    float* dinv   = (float*)(ws + OFF_DINV);
    float* ss     = (float*)(ws + OFF_SS);
    int*   bsum   = (int*)(ws + OFF_BSUM);
    int*   boff   = (int*)(ws + OFF_BOFF);
    int*   col    = (int*)(ws + OFF_COL);
    float* coef   = (float*)(ws + OFF_COEF);
    unsigned short* bufH = (unsigned short*)(ws + OFF_BUFH);
    float* bufA   = (float*)(ws + OFF_BUFA);

    hipMemsetAsync(ws, 0, ZERO_BYTES, stream);

    const int EB = (EDGES + 255) / 256;
    deg_kernel<<<EB, 256, 0, stream>>>(ei + EDGES, degcnt);
    scan1_kernel<<<SCANB, 256, 0, stream>>>(degcnt, bsum);
    scan2_kernel<<<1, 256, 0, stream>>>(bsum, boff, rowptr);
    scan3_kernel<<<SCANB, 256, 0, stream>>>(degcnt, boff, rowptr, dinv);
    fill_kernel<<<EB, 256, 0, stream>>>(ei, ei + EDGES, rowptr, cursor, dinv, col, coef);

    dim3 gg((NODES + 63) / 64, 2);
    const int AGB = (NODES * 64 + 255) / 256;  // 12500

    // layer 0
    gemm_kernel<<<gg, 256, 0, stream>>>(x, W0, bufH, nullptr, nullptr);
    agg_kernel<<<AGB, 256, 0, stream>>>(bufH, rowptr, col, coef, bufA);
    stats_kernel<<<512, 256, 0, stream>>>(bufA, stats + 0);
    finalize_kernel<<<1, 128, 0, stream>>>(stats + 0, g0, be0, ss + 0);
    // layer 1 (BN0+ReLU fused into A-load)
    gemm_kernel<<<gg, 256, 0, stream>>>(bufA, W1, bufH, ss + 0, ss + 128);
    agg_kernel<<<AGB, 256, 0, stream>>>(bufH, rowptr, col, coef, bufA);
    stats_kernel<<<512, 256, 0, stream>>>(bufA, stats + 256);
    finalize_kernel<<<1, 128, 0, stream>>>(stats + 256, g1, be1, ss + 256);
    // layer 2
    gemm_kernel<<<gg, 256, 0, stream>>>(bufA, W2, bufH, ss + 256, ss + 384);
    agg_kernel<<<AGB, 256, 0, stream>>>(bufH, rowptr, col, coef, bufA);
    stats_kernel<<<512, 256, 0, stream>>>(bufA, stats + 512);
    finalize_kernel<<<1, 128, 0, stream>>>(stats + 512, g2, be2, ss + 512);
    // pool + head (BN2+ReLU fused into pool)
    bounds_kernel<<<1, 64, 0, stream>>>(batch, pcnt);
    pool_kernel<<<(NODES + 127) / 128, 128, 0, stream>>>(bufA, batch, ss + 512, psum);
    head_kernel<<<1, 512, 0, stream>>>(psum, pcnt, Wh, bh, out);
}

// Round 7
// 418.422 us; speedup vs baseline: 2.4724x; 1.1714x over previous
//
#include <hip/hip_runtime.h>

#define NODES 50000
#define EDGES 600000
#define C     128
#define NGRAPH 64
#define EPSBN 1e-5f
#define SCANB 196   // 196*256 = 50176 >= NODES

typedef short v8s __attribute__((ext_vector_type(8)));
typedef float v4f __attribute__((ext_vector_type(4)));

// ---------------- workspace layout (bytes) ----------------
// zeroed region (one hipMemsetAsync):
#define OFF_DEGCNT 0u          // int[50048]   -> 200192
#define OFF_CURSOR 200192u     // int[50048]   -> 400384
#define OFF_STATS  400384u     // float[768]   -> 403456
#define OFF_PSUM   403456u     // float[8192]  -> 436224
#define ZERO_BYTES 436224u
// non-zeroed:
#define OFF_ROWPTR 436224u     // int[50056]   -> 636448
#define OFF_DINV   636448u     // float[50048] -> 836640
#define OFF_SS     836640u     // float[768]   -> 839712
#define OFF_BSUM   839712u     // int[256]     -> 840736
#define OFF_BOFF   840736u     // int[256]     -> 841760
#define OFF_BPACK  841760u     // short[3*16384] -> 940064  (packed bf16 W frags)
#define OFF_COL    940064u     // int[600064]  -> 3340320
#define OFF_COEF   3340320u    // float[600064]-> 5740576
#define OFF_BUFH   5740576u    // ushort[6400000] (bf16 H) -> 18540576
#define OFF_BUFA   18540576u   // ushort[6400000] (bf16 A) -> 31340576

// fp32 -> bf16 round-to-nearest-even
static __device__ __forceinline__ unsigned short f2bf(float f) {
    unsigned u = __float_as_uint(f);
    u += 0x7fffu + ((u >> 16) & 1u);
    return (unsigned short)(u >> 16);
}
static __device__ __forceinline__ float bflo(unsigned u) { return __uint_as_float(u << 16); }
static __device__ __forceinline__ float bfhi(unsigned u) { return __uint_as_float(u & 0xffff0000u); }
static __device__ __forceinline__ float bf1(unsigned short s) { return __uint_as_float(((unsigned)s) << 16); }

// ---------------- CSR build ----------------
__global__ void deg_kernel(const int* __restrict__ dst, int* __restrict__ degcnt) {
    int e = blockIdx.x * 256 + threadIdx.x;
    if (e < EDGES) atomicAdd(&degcnt[dst[e]], 1);
}

__global__ __launch_bounds__(256) void scan1_kernel(const int* __restrict__ degcnt,
                                                    int* __restrict__ bsum) {
    int t = threadIdx.x;
    int i = blockIdx.x * 256 + t;
    int v = (i < NODES) ? degcnt[i] : 0;
    __shared__ int sc[256];
    sc[t] = v; __syncthreads();
    for (int off = 128; off > 0; off >>= 1) {
        if (t < off) sc[t] += sc[t + off];
        __syncthreads();
    }
    if (t == 0) bsum[blockIdx.x] = sc[0];
}

__global__ __launch_bounds__(256) void scan2_kernel(const int* __restrict__ bsum,
                                                    int* __restrict__ boff,
                                                    int* __restrict__ rowptr) {
    int t = threadIdx.x;
    int v = (t < SCANB) ? bsum[t] : 0;
    __shared__ int sc[256];
    sc[t] = v; __syncthreads();
    for (int off = 1; off < 256; off <<= 1) {
        int u = 0; if (t >= off) u = sc[t - off];
        __syncthreads(); sc[t] += u; __syncthreads();
    }
    if (t < SCANB) boff[t] = sc[t] - v;   // exclusive
    if (t == 0) rowptr[NODES] = EDGES;
}

__global__ __launch_bounds__(256) void scan3_kernel(const int* __restrict__ degcnt,
                                                    const int* __restrict__ boff,
                                                    int* __restrict__ rowptr,
                                                    float* __restrict__ dinv) {
    int t = threadIdx.x;
    int i = blockIdx.x * 256 + t;
    int v = (i < NODES) ? degcnt[i] : 0;
    __shared__ int sc[256];
    sc[t] = v; __syncthreads();
    for (int off = 1; off < 256; off <<= 1) {
        int u = 0; if (t >= off) u = sc[t - off];
        __syncthreads(); sc[t] += u; __syncthreads();
    }
    if (i < NODES) {
        rowptr[i] = boff[blockIdx.x] + sc[t] - v;
        dinv[i] = (v > 0) ? rsqrtf((float)v) : 0.f;
    }
}

__global__ void fill_kernel(const int* __restrict__ src, const int* __restrict__ dst,
                            const int* __restrict__ rowptr, int* __restrict__ cursor,
                            const float* __restrict__ dinv,
                            int* __restrict__ col, float* __restrict__ coef) {
    int e = blockIdx.x * 256 + threadIdx.x;
    if (e < EDGES) {
        int s = src[e], d = dst[e];
        int pos = rowptr[d] + atomicAdd(&cursor[d], 1);
        col[pos] = s;
        coef[pos] = dinv[s] * dinv[d];
    }
}

// ---------------- W pre-pack: fp32 [128k][128n] -> bf16 B-fragment layout ----------------
// frag layout per layer: [(nb*4+ks)*64 + lane] * 8 shorts; lane = q*16+n holds
// B[k=32ks+8q+j][n'=nb*16+n] for j=0..7.
__global__ __launch_bounds__(256) void pack_kernel(const float* __restrict__ W0,
                                                   const float* __restrict__ W1,
                                                   const float* __restrict__ W2,
                                                   short* __restrict__ Bp) {
    int id = blockIdx.x * 256 + threadIdx.x;   // 24*256 = 6144 = 3*2048 frags
    int l = id >> 11;
    int f = id & 2047;
    const float* W = (l == 0) ? W0 : (l == 1) ? W1 : W2;
    int lane = f & 63, nbks = f >> 6;
    int nb = nbks >> 2, ks = nbks & 3;
    int q = lane >> 4, n = lane & 15;
    v8s o;
    #pragma unroll
    for (int j = 0; j < 8; j++)
        o[j] = (short)f2bf(W[(ks * 32 + q * 8 + j) * 128 + nb * 16 + n]);
    *(v8s*)&Bp[id * 8] = o;
}

// ---------------- MFMA GEMM: H[64 rows x 128 cols] per block, bf16 in/out ----------------
// block 256 = 4 waves; wave mb computes rows r0+16mb..+15, all 128 cols.
// LDS: Apk = 16 segs x (1024+16) B (pad kills staging bank conflicts); Bpk flat 32 KB.
template<bool A32>
__global__ __launch_bounds__(256) void gemm_kernel(
    const void* __restrict__ Ain, const short* __restrict__ Bpg,
    unsigned short* __restrict__ Hout, const float* __restrict__ ss) {
    __shared__ short Apk[8320];    // 16 segs * 520 shorts
    __shared__ short Bpk[16384];
    int t = threadIdx.x;
    int r0 = blockIdx.x * 64;
    // stage B: flat 32 KB copy
    #pragma unroll
    for (int i = 0; i < 8; i++) {
        int c = t + 256 * i;
        *(v8s*)&Bpk[c * 8] = *(const v8s*)&Bpg[c * 8];
    }
    // stage A: 1024 frags, BN+ReLU fused, pack to MFMA A-layout
    #pragma unroll
    for (int i = 0; i < 4; i++) {
        int f = t + 256 * i;
        int row = f >> 4, kf = f & 15;
        int gr = r0 + row;
        float v[8];
        #pragma unroll
        for (int e = 0; e < 8; e++) v[e] = 0.f;
        if (gr < NODES) {
            if (A32) {
                const float* Ap = (const float*)Ain + (size_t)gr * C + kf * 8;
                float4 lo = *(const float4*)Ap;
                float4 hi = *(const float4*)(Ap + 4);
                v[0]=lo.x; v[1]=lo.y; v[2]=lo.z; v[3]=lo.w;
                v[4]=hi.x; v[5]=hi.y; v[6]=hi.z; v[7]=hi.w;
            } else {
                const unsigned short* Ap = (const unsigned short*)Ain + (size_t)gr * C + kf * 8;
                uint4 raw = *(const uint4*)Ap;
                v[0]=bflo(raw.x); v[1]=bfhi(raw.x); v[2]=bflo(raw.y); v[3]=bfhi(raw.y);
                v[4]=bflo(raw.z); v[5]=bfhi(raw.z); v[6]=bflo(raw.w); v[7]=bfhi(raw.w);
            }
        }
        if (ss) {
            #pragma unroll
            for (int e = 0; e < 8; e++) {
                int c = kf * 8 + e;
                v[e] = fmaxf(0.f, fmaf(v[e], ss[c], ss[128 + c]));
            }
        }
        v8s af;
        #pragma unroll
        for (int e = 0; e < 8; e++) af[e] = (short)f2bf(v[e]);
        int mb = row >> 4, m = row & 15, ks = kf >> 2, q = kf & 3;
        *(v8s*)&Apk[(mb * 4 + ks) * 520 + (q * 16 + m) * 8] = af;
    }
    __syncthreads();
    int lane = t & 63, mb = t >> 6;
    v4f acc[8];
    #pragma unroll
    for (int nb = 0; nb < 8; nb++) acc[nb] = 0.f;
    #pragma unroll
    for (int ks = 0; ks < 4; ks++) {
        v8s aF = *(const v8s*)&Apk[(mb * 4 + ks) * 520 + lane * 8];
        #pragma unroll
        for (int nb = 0; nb < 8; nb++) {
            v8s bF = *(const v8s*)&Bpk[((nb * 4 + ks) * 64 + lane) * 8];
            acc[nb] = __builtin_amdgcn_mfma_f32_16x16x32_bf16(aF, bF, acc[nb], 0, 0, 0);
        }
    }
    // epilogue: C/D frag (col=lane&15, row=(lane>>4)*4+reg) -> LDS -> coalesced bf16 store
    // reuse Apk region mb: 2080 shorts >= 16x128
    int q = lane >> 4, n = lane & 15;
    #pragma unroll
    for (int nb = 0; nb < 8; nb++) {
        #pragma unroll
        for (int r = 0; r < 4; r++)
            Apk[mb * 2080 + (q * 4 + r) * 128 + nb * 16 + n] = (short)f2bf(acc[nb][r]);
    }
    // wave-local: same wave wrote all 16 rows; lgkmcnt ordering suffices (no barrier)
    #pragma unroll
    for (int i = 0; i < 4; i++) {
        int idx = lane + 64 * i;
        int row = idx >> 4, colv = (idx & 15) * 8;
        int gr = r0 + mb * 16 + row;
        if (gr < NODES)
            *(uint4*)&Hout[(size_t)gr * C + colv] = *(const uint4*)&Apk[mb * 2080 + row * 128 + colv];
    }
}

// ---------------- aggregation: wave/node, bf16 gather, 8-way MLP unroll, bf16 out ---------
__global__ __launch_bounds__(256) void agg_kernel(
    const unsigned short* __restrict__ H, const int* __restrict__ rowptr,
    const int* __restrict__ col, const float* __restrict__ coef,
    unsigned short* __restrict__ Aout) {
    int wid = (blockIdx.x * 256 + threadIdx.x) >> 6;
    int lane = threadIdx.x & 63;
    if (wid >= NODES) return;
    int beg = rowptr[wid], end = rowptr[wid + 1];
    const unsigned short* Hl = H + lane * 2;
    float ax = 0.f, ay = 0.f;
    int i = beg;
    for (; i + 8 <= end; i += 8) {
        int s[8]; float w[8]; unsigned u[8];
        #pragma unroll
        for (int j = 0; j < 8; j++) s[j] = col[i + j];
        #pragma unroll
        for (int j = 0; j < 8; j++) w[j] = coef[i + j];
        #pragma unroll
        for (int j = 0; j < 8; j++) u[j] = *(const unsigned*)&Hl[s[j] * C];
        #pragma unroll
        for (int j = 0; j < 8; j++) {
            ax = fmaf(w[j], bflo(u[j]), ax); ay = fmaf(w[j], bfhi(u[j]), ay);
        }
    }
    for (; i + 4 <= end; i += 4) {
        int s[4]; float w[4]; unsigned u[4];
        #pragma unroll
        for (int j = 0; j < 4; j++) s[j] = col[i + j];
        #pragma unroll
        for (int j = 0; j < 4; j++) w[j] = coef[i + j];
        #pragma unroll
        for (int j = 0; j < 4; j++) u[j] = *(const unsigned*)&Hl[s[j] * C];
        #pragma unroll
        for (int j = 0; j < 4; j++) {
            ax = fmaf(w[j], bflo(u[j]), ax); ay = fmaf(w[j], bfhi(u[j]), ay);
        }
    }
    for (; i < end; i++) {
        unsigned u = *(const unsigned*)&Hl[col[i] * C];
        float w0 = coef[i];
        ax = fmaf(w0, bflo(u), ax); ay = fmaf(w0, bfhi(u), ay);
    }
    unsigned o = ((unsigned)f2bf(ay) << 16) | (unsigned)f2bf(ax);
    *(unsigned*)&Aout[(size_t)wid * C + lane * 2] = o;
}

// ---------------- BN stats on bf16 activations ----------------
__global__ __launch_bounds__(256) void stats_kernel(const unsigned short* __restrict__ X,
                                                    float* __restrict__ stats) {
    int t = threadIdx.x, lane = t & 63, rg = t >> 6;
    float s0 = 0.f, s1 = 0.f, q0 = 0.f, q1 = 0.f;
    for (int r = blockIdx.x * 4 + rg; r < NODES; r += 1024) {
        unsigned u = *(const unsigned*)&X[(size_t)r * C + lane * 2];
        float x0 = bflo(u), x1 = bfhi(u);
        s0 += x0; s1 += x1;
        q0 = fmaf(x0, x0, q0); q1 = fmaf(x1, x1, q1);
    }
    __shared__ float red[1024];
    red[t] = s0; red[256 + t] = s1; red[512 + t] = q0; red[768 + t] = q1;
    __syncthreads();
    if (t < 64) {
        s0 = red[t] + red[t + 64] + red[t + 128] + red[t + 192];
        s1 = red[256 + t] + red[320 + t] + red[384 + t] + red[448 + t];
        q0 = red[512 + t] + red[576 + t] + red[640 + t] + red[704 + t];
        q1 = red[768 + t] + red[832 + t] + red[896 + t] + red[960 + t];
        atomicAdd(&stats[2 * t], s0);
        atomicAdd(&stats[2 * t + 1], s1);
        atomicAdd(&stats[128 + 2 * t], q0);
        atomicAdd(&stats[128 + 2 * t + 1], q1);
    }
}

__global__ void finalize_kernel(const float* __restrict__ stats, const float* __restrict__ g,
                                const float* __restrict__ be, float* __restrict__ ss) {
    int c = threadIdx.x;  // 128
    float mean = stats[c] * (1.0f / NODES);
    float var = stats[128 + c] * (1.0f / NODES) - mean * mean;
    float sc = g[c] * rsqrtf(var + EPSBN);
    ss[c] = sc;
    ss[128 + c] = be[c] - mean * sc;
}

// ---------------- pooling (BN2+ReLU fused), bf16 input ----------------
__global__ __launch_bounds__(128) void pool_kernel(const unsigned short* __restrict__ X,
                                                   const int* __restrict__ batch,
                                                   const float* __restrict__ ss,
                                                   float* __restrict__ psum) {
    int c = threadIdx.x;
    int r0 = blockIdx.x * 128;
    if (r0 >= NODES) return;
    int rend = min(r0 + 128, NODES);
    float sc = ss[c], sh = ss[128 + c];
    float acc = 0.f;
    int cur = batch[r0];
    for (int r = r0; r < rend; r++) {
        int g = batch[r];
        if (g != cur) { atomicAdd(&psum[cur * C + c], acc); acc = 0.f; cur = g; }
        float v = bf1(X[(size_t)r * C + c]);
        v = fmaxf(0.f, fmaf(v, sc, sh));
        acc += v;
    }
    atomicAdd(&psum[cur * C + c], acc);
}

// ---------------- head (+ per-graph counts via binary search on sorted batch) -------------
__global__ __launch_bounds__(512) void head_kernel(const float* __restrict__ psum,
                                                   const int* __restrict__ batch,
                                                   const float* __restrict__ Wh,
                                                   const float* __restrict__ bh,
                                                   float* __restrict__ out) {
    __shared__ int sb[65];
    int t = threadIdx.x;
    if (t <= 64) {
        int lo = 0, hi = NODES;
        while (lo < hi) { int m = (lo + hi) >> 1; if (batch[m] < t) lo = m + 1; else hi = m; }
        sb[t] = lo;  // lower_bound(t); sb[64] = NODES
    }
    __syncthreads();
    int g = t >> 3, o = t & 7;
    float inv = 1.0f / fmaxf((float)(sb[g + 1] - sb[g]), 1.0f);
    float acc = 0.f;
    for (int c = 0; c < C; c++) acc = fmaf(psum[g * C + c], Wh[c * 8 + o], acc);
    out[t] = fmaf(acc, inv, bh[o]);
}

extern "C" void kernel_launch(void* const* d_in, const int* in_sizes, int n_in,
                              void* d_out, int out_size, void* d_ws, size_t ws_size,
                              hipStream_t stream) {
    (void)in_sizes; (void)n_in; (void)out_size; (void)ws_size;
    const float* x    = (const float*)d_in[0];
    const int*   ei   = (const int*)d_in[1];      // [2, EDGES]: src then dst
    const int*   batch= (const int*)d_in[2];
    const float* W0   = (const float*)d_in[3];
    const float* g0   = (const float*)d_in[5];
    const float* be0  = (const float*)d_in[6];
    const float* W1   = (const float*)d_in[7];
    const float* g1   = (const float*)d_in[9];
    const float* be1  = (const float*)d_in[10];
    const float* W2   = (const float*)d_in[11];
    const float* g2   = (const float*)d_in[13];
    const float* be2  = (const float*)d_in[14];
    const float* Wh   = (const float*)d_in[15];
    const float* bh   = (const float*)d_in[16];
    float* out = (float*)d_out;

    char* ws = (char*)d_ws;
    int*   degcnt = (int*)(ws + OFF_DEGCNT);
    int*   cursor = (int*)(ws + OFF_CURSOR);
    float* stats  = (float*)(ws + OFF_STATS);
    float* psum   = (float*)(ws + OFF_PSUM);
    int*   rowptr = (int*)(ws + OFF_ROWPTR);
    float* dinv   = (float*)(ws + OFF_DINV);
    float* ss     = (float*)(ws + OFF_SS);
    int*   bsum   = (int*)(ws + OFF_BSUM);
    int*   boff   = (int*)(ws + OFF_BOFF);
    short* bpack  = (short*)(ws + OFF_BPACK);
    int*   col    = (int*)(ws + OFF_COL);
    float* coef   = (float*)(ws + OFF_COEF);
    unsigned short* bufH = (unsigned short*)(ws + OFF_BUFH);
    unsigned short* bufA = (unsigned short*)(ws + OFF_BUFA);

    (void)hipMemsetAsync(ws, 0, ZERO_BYTES, stream);

    const int EB = (EDGES + 255) / 256;
    deg_kernel<<<EB, 256, 0, stream>>>(ei + EDGES, degcnt);
    scan1_kernel<<<SCANB, 256, 0, stream>>>(degcnt, bsum);
    scan2_kernel<<<1, 256, 0, stream>>>(bsum, boff, rowptr);
    scan3_kernel<<<SCANB, 256, 0, stream>>>(degcnt, boff, rowptr, dinv);
    fill_kernel<<<EB, 256, 0, stream>>>(ei, ei + EDGES, rowptr, cursor, dinv, col, coef);
    pack_kernel<<<24, 256, 0, stream>>>(W0, W1, W2, bpack);

    const int GB = (NODES + 63) / 64;            // 782
    const int AGB = (NODES * 64 + 255) / 256;    // 12500

    // layer 0 (A = fp32 x)
    gemm_kernel<true><<<GB, 256, 0, stream>>>(x, bpack, bufH, nullptr);
    agg_kernel<<<AGB, 256, 0, stream>>>(bufH, rowptr, col, coef, bufA);
    stats_kernel<<<256, 256, 0, stream>>>(bufA, stats + 0);
    finalize_kernel<<<1, 128, 0, stream>>>(stats + 0, g0, be0, ss + 0);
    // layer 1 (A = bf16 bufA, BN0+ReLU fused in staging)
    gemm_kernel<false><<<GB, 256, 0, stream>>>(bufA, bpack + 16384, bufH, ss + 0);
    agg_kernel<<<AGB, 256, 0, stream>>>(bufH, rowptr, col, coef, bufA);
    stats_kernel<<<256, 256, 0, stream>>>(bufA, stats + 256);
    finalize_kernel<<<1, 128, 0, stream>>>(stats + 256, g1, be1, ss + 256);
    // layer 2
    gemm_kernel<false><<<GB, 256, 0, stream>>>(bufA, bpack + 32768, bufH, ss + 256);
    agg_kernel<<<AGB, 256, 0, stream>>>(bufH, rowptr, col, coef, bufA);
    stats_kernel<<<256, 256, 0, stream>>>(bufA, stats + 512);
    finalize_kernel<<<1, 128, 0, stream>>>(stats + 512, g2, be2, ss + 512);
    // pool + head (BN2+ReLU fused into pool; counts via binary search in head)
    pool_kernel<<<(NODES + 127) / 128, 128, 0, stream>>>(bufA, batch, ss + 512, psum);
    head_kernel<<<1, 512, 0, stream>>>(psum, batch, Wh, bh, out);
}